// Round 9
// baseline (320.831 us; speedup 1.0000x reference)
//
#include <hip/hip_runtime.h>
#include <hip/hip_bf16.h>

typedef unsigned short u16;
typedef unsigned int   u32;
typedef unsigned long long u64;

#define SEQ 1024
#define EMB 1024
#define NH  16
#define DKH 64

// 0.125 (1/sqrt(64)) * log2(e): folded into Wq/bq so attn uses exp2 directly
#define QSCALE 0.18033688f

typedef __attribute__((ext_vector_type(8))) short short8;
typedef __attribute__((ext_vector_type(4))) float floatx4;

__device__ __forceinline__ float b2f(u16 u) {
  return __uint_as_float(((u32)u) << 16);
}
__device__ __forceinline__ u16 f2b(float f) {
  u32 u = __float_as_uint(f);
  u32 r = u + 0x7fffu + ((u >> 16) & 1u);   // RNE
  return (u16)(r >> 16);
}

// async global->LDS, 16 B per lane; LDS dst = wave-uniform base + lane*16
__device__ __forceinline__ void glds16(const u16* g, u16* l) {
  __builtin_amdgcn_global_load_lds(
      (const __attribute__((address_space(1))) u32*)g,
      (__attribute__((address_space(3))) u32*)l, 16, 0, 0);
}

// ---------- probe the two 8M-element buffers ----------
// flags[0]=xIsB, flags[1]=x storage (1=bf16,0=fp32), flags[2]=mask bytes (1) vs int32 (0)
__global__ __launch_bounds__(256) void probe_inputs(const u32* __restrict__ A,
                                                    const u32* __restrict__ B,
                                                    int* __restrict__ flags) {
  __shared__ int mA, mB, mBig, xB16;
  if (threadIdx.x == 0) { mA = 0; mB = 0; mBig = 0; xB16 = 0; }
  __syncthreads();
  int la = 0, lb = 0;
  for (int i = threadIdx.x; i < 4096; i += 256) {
    if ((A[i] & 0xFEFEFEFEu) == 0) la++;
    if ((B[i] & 0xFEFEFEFEu) == 0) lb++;
  }
  atomicAdd(&mA, la); atomicAdd(&mB, lb);
  __syncthreads();
  const int xIsB = (mA > mB) ? 1 : 0;
  const u32* X = xIsB ? B : A;
  const u32* M = xIsB ? A : B;
  int big = 0, cnt = 0;
  for (int i = threadIdx.x; i < 4096; i += 256)
    if (M[i] > 1u) big = 1;
  for (int i = threadIdx.x; i < 2048; i += 256) {
    u16 v = (u16)(X[i] & 0xffffu);
    int e = (v >> 7) & 0xFF;
    if (e >= 110 && e <= 135) cnt++;
  }
  if (big) atomicOr(&mBig, 1);
  atomicAdd(&xB16, cnt);
  __syncthreads();
  if (threadIdx.x == 0) {
    flags[0] = xIsB;
    flags[1] = (xB16 > 1500) ? 1 : 0;
    flags[2] = mBig;
  }
}

// ============================================================================
// Fused preprocessing: ONE dispatch replaces convert_x + build_maskbits +
// transpose_convert_w4 + convert_biases (all independent given flags).
// blockIdx.x ranges: [0,8192) convert_x; [8192,9216) maskbits;
// [9216,13312) weight transpose (idx = z*1024 + by*32 + bx); [13312,13316) biases.
// ============================================================================
__global__ __launch_bounds__(256) void preprocess(
    const void* __restrict__ bigA, const void* __restrict__ bigB,
    const int* __restrict__ flags,
    u16* __restrict__ xb, u32* __restrict__ maskbits,
    const void* __restrict__ w0, const void* __restrict__ w1,
    const void* __restrict__ w2, const void* __restrict__ w3,
    u16* __restrict__ outQKV, u16* __restrict__ outO,
    const void* __restrict__ b0, const void* __restrict__ b1,
    const void* __restrict__ b2, const void* __restrict__ b3,
    float* __restrict__ biasf) {
  __shared__ float tile[32][33];
  const int bidg = blockIdx.x;
  const int t = threadIdx.x;
  const int amode = flags[1];

  if (bidg < 8192) {
    // ---- convert x to bf16 (or copy) ----
    const void* x = flags[0] ? bigB : bigA;
    int i = (bidg * 256 + t) * 4;
    if (amode) {
      *(ushort4*)(xb + i) = *(const ushort4*)((const u16*)x + i);
    } else {
      float4 v = *(const float4*)((const float*)x + i);
      ushort4 o;
      o.x = f2b(v.x); o.y = f2b(v.y); o.z = f2b(v.z); o.w = f2b(v.w);
      *(ushort4*)(xb + i) = o;
    }
  } else if (bidg < 9216) {
    // ---- pack mask KEEP bits via ballot ----
    const void* mask = flags[0] ? bigA : bigB;
    const int mbyte = flags[2];
    const int lane = t & 63, wv = t >> 6;
    const u64 base0 = (u64)(bidg - 8192) * 8192;
#pragma unroll 4
    for (int k = 0; k < 32; k++) {
      u64 idx = base0 + k * 256 + t;
      int v;
      if (mbyte) v = ((const unsigned char*)mask)[idx] == 0;
      else       v = ((const u32*)mask)[idx] == 0;
      u64 b = __ballot(v);
      if (lane == 0) {
        u64 wbase = (base0 + k * 256 + wv * 64) >> 5;
        maskbits[wbase]     = (u32)b;
        maskbits[wbase + 1] = (u32)(b >> 32);
      }
    }
  } else if (bidg < 13312) {
    // ---- transpose(+convert) the 4 weights ----
    const int idx = bidg - 9216;
    const int z = idx >> 10;
    const int byi = (idx & 1023) >> 5;
    const int bxi = idx & 31;
    const void* in = (z == 0) ? w0 : (z == 1) ? w1 : (z == 2) ? w2 : w3;
    u16* out = (z < 3) ? (outQKV + (u64)z * EMB * EMB) : outO;
    const float scale = (z == 0) ? QSCALE : 1.0f;
    const int tx = t & 31;
    const int ty = t >> 5;
    const int bx = bxi * 32, by = byi * 32;
    if (amode) {
      const u16* inb = (const u16*)in;
#pragma unroll
      for (int r = ty; r < 32; r += 8)
        tile[r][tx] = b2f(inb[(u64)(by + r) * EMB + bx + tx]);
    } else {
      const float* inf = (const float*)in;
#pragma unroll
      for (int r = ty; r < 32; r += 8)
        tile[r][tx] = inf[(u64)(by + r) * EMB + bx + tx];
    }
    __syncthreads();
#pragma unroll
    for (int r = ty; r < 32; r += 8)
      out[(u64)(bx + r) * EMB + by + tx] = f2b(tile[tx][r] * scale);
  } else {
    // ---- biases (bq pre-scaled) ----
    const int widx = bidg - 13312;
    const void* ptrs[4] = {b0, b1, b2, b3};
    const void* p = ptrs[widx];
    const float scale = (widx == 0) ? QSCALE : 1.0f;
    for (int i = t; i < 1024; i += 256) {
      float v = amode ? b2f(((const u16*)p)[i]) : ((const float*)p)[i];
      biasf[widx * 1024 + i] = v * scale;
    }
  }
}

// ============================================================================
// GEMM (round-6 proven core): 256x128 tile, BK=64, 8 waves, double-buffered
// LDS (96 KB), counted vmcnt(6) + raw s_barrier (T3-lite), setprio (T5),
// XOR-swizzled LDS via inverse-swizzled global_load_lds source (T2/m173).
// NEW: XCD-chunked blockIdx swizzle (T1, bijective since nwg % 8 == 0) so
// each XCD gets contiguous bN panels -> B fetched once per XCD, not 8x.
// V-section epilogue writes V^T directly (LDS transpose).
// ============================================================================

// epilogue mode 0: QKV (Q/K head-scatter u16, V transposed [d][s]); 1: fp32
template <int OUTMODE>
__device__ __forceinline__ void gemm_core(
    const u16* __restrict__ X, const u16* __restrict__ Wt,
    const float* __restrict__ bias,
    u16* __restrict__ Qg, u16* __restrict__ Kg, u16* __restrict__ Vt,
    float* __restrict__ outf, int row0) {
  __shared__ __align__(16) u16 lds[2][(256 + 128) * 64];
  const int t = threadIdx.x;
  const int lane = t & 63;
  const int w = t >> 6;                 // 0..7
  const int wr = w >> 1, wc = w & 1;    // wave tile: rows wr*64, cols wc*64
  const int l15 = lane & 15, l4 = lane >> 4;

  // T1: XCD-chunked bijective swizzle (nwg = gridDim.x*gridDim.y, % 8 == 0)
  const int nwg = gridDim.x * gridDim.y;
  const int bid0 = blockIdx.y * gridDim.x + blockIdx.x;
  const int cpx = nwg >> 3;
  const int swz = (bid0 & 7) * cpx + (bid0 >> 3);
  const int bM = (swz % gridDim.x) * 256;
  const int bN = (swz / gridDim.x) * 128;

  const int r7 = l15 & 7;
  const int cA = (l4 ^ r7) << 3;        // swizzled chunk for k-half 0
  const int cB = (l4 ^ r7 ^ 4) << 3;    // swizzled chunk for k-half 1

  floatx4 acc[4][4];
#pragma unroll
  for (int i = 0; i < 4; i++)
#pragma unroll
    for (int j = 0; j < 4; j++)
      acc[i][j] = (floatx4){0.f, 0.f, 0.f, 0.f};

  // staging: round covers 64 rows; wave w rows w*8+(lane>>3); chunk lane&7,
  // inverse-swizzled at the global source (LDS dst stays linear).
  const int srow = w * 8 + (lane >> 3);
  const int schk = ((lane & 7) ^ (lane >> 3)) << 3;
  const u16* Ap = X + (u64)(row0 + bM + srow) * EMB + schk;
  const u16* Bp = Wt + (u64)(bN + srow) * EMB + schk;
  u16* Ad0 = &lds[0][w * 512];
  u16* Bd0 = &lds[0][16384 + w * 512];
  u16* Ad1 = &lds[1][w * 512];
  u16* Bd1 = &lds[1][16384 + w * 512];

  auto stage = [&](u16* Ad, u16* Bd, int k0) {
    glds16(Ap + k0, Ad);
    glds16(Ap + k0 + 64 * EMB, Ad + 4096);
    glds16(Ap + k0 + 128 * EMB, Ad + 8192);
    glds16(Ap + k0 + 192 * EMB, Ad + 12288);
    glds16(Bp + k0, Bd);
    glds16(Bp + k0 + 64 * EMB, Bd + 4096);
  };

  auto compute = [&](const u16* __restrict__ Ab, const u16* __restrict__ Bb) {
    short8 af[2][2], bfr[4][2];
#pragma unroll
    for (int n = 0; n < 4; n++) {
      const int gr = (wc * 64 + n * 16 + l15) * 64;
      bfr[n][0] = *(const short8*)(&Bb[gr + cA]);
      bfr[n][1] = *(const short8*)(&Bb[gr + cB]);
    }
#pragma unroll
    for (int mh = 0; mh < 2; mh++) {
      short8 af2[2][2];
#pragma unroll
      for (int m = 0; m < 2; m++) {
        const int fr = (wr * 64 + mh * 32 + m * 16 + l15) * 64;
        af2[m][0] = *(const short8*)(&Ab[fr + cA]);
        af2[m][1] = *(const short8*)(&Ab[fr + cB]);
      }
      __builtin_amdgcn_s_setprio(1);
#pragma unroll
      for (int m = 0; m < 2; m++)
#pragma unroll
        for (int n = 0; n < 4; n++) {
          acc[mh * 2 + m][n] = __builtin_amdgcn_mfma_f32_16x16x32_bf16(
              af2[m][0], bfr[n][0], acc[mh * 2 + m][n], 0, 0, 0);
          acc[mh * 2 + m][n] = __builtin_amdgcn_mfma_f32_16x16x32_bf16(
              af2[m][1], bfr[n][1], acc[mh * 2 + m][n], 0, 0, 0);
        }
      __builtin_amdgcn_s_setprio(0);
      (void)af[0][0];
    }
  };

  stage(Ad0, Bd0, 0);
  // 16 K-tiles, 2 per unrolled step; counted vmcnt keeps next tile in flight
  for (int k0 = 0; k0 < EMB; k0 += 128) {
    stage(Ad1, Bd1, k0 + 64);
    asm volatile("s_waitcnt vmcnt(6)" ::: "memory");
    asm volatile("s_barrier" ::: "memory");
    compute(&lds[0][0], &lds[0][16384]);
    asm volatile("s_barrier" ::: "memory");
    if (k0 + 128 < EMB) {
      stage(Ad0, Bd0, k0 + 128);
      asm volatile("s_waitcnt vmcnt(6)" ::: "memory");
    } else {
      asm volatile("s_waitcnt vmcnt(0)" ::: "memory");
    }
    asm volatile("s_barrier" ::: "memory");
    compute(&lds[1][0], &lds[1][16384]);
    asm volatile("s_barrier" ::: "memory");
  }

  if (OUTMODE == 0) {
    const int sec = bN >> 10;               // 0=Q,1=K,2=V (block-uniform)
    if (sec < 2) {
      u16* outp = (sec == 0) ? Qg : Kg;
#pragma unroll
      for (int n = 0; n < 4; n++) {
        int col = bN + wc * 64 + n * 16 + l15;
        float bv = bias[col];
        int colh = col & 1023;
        int h = colh >> 6, d = colh & 63;
#pragma unroll
        for (int mt = 0; mt < 4; mt++) {
#pragma unroll
          for (int r = 0; r < 4; r++) {
            int row = bM + wr * 64 + mt * 16 + l4 * 4 + r;
            float v = acc[mt][n][r] + bv;
            int nb = row >> 10, s = row & 1023;
            outp[((u64)((nb * NH + h) * SEQ + s)) * DKH + d] = f2b(v);
          }
        }
      }
    } else {
      // V section: transpose through LDS, write Vt[d][s] coalesced.
      // ldt: [128 d][256 s] u16, XOR-swizzled 8-elem chunks.
      u16* ldt = &lds[0][0];                // 64 KB of the 96 KB block
#pragma unroll
      for (int n = 0; n < 4; n++) {
        const int dl = wc * 64 + n * 16 + l15;          // 0..127
        const float bv = bias[bN + dl];
#pragma unroll
        for (int mt = 0; mt < 4; mt++) {
          const int sb = wr * 64 + mt * 16 + l4 * 4;    // mult of 4
          const int sp = sb ^ ((dl & 7) << 3);          // stays 4-aligned
          u32 w0 = (u32)f2b(acc[mt][n][0] + bv) |
                   ((u32)f2b(acc[mt][n][1] + bv) << 16);
          u32 w1 = (u32)f2b(acc[mt][n][2] + bv) |
                   ((u32)f2b(acc[mt][n][3] + bv) << 16);
          *(u32*)(&ldt[dl * 256 + sp])     = w0;
          *(u32*)(&ldt[dl * 256 + sp + 2]) = w1;
        }
      }
      __syncthreads();
      const int d  = t >> 2;          // 0..127
      const int sq = (t & 3) * 64;    // s quarter
      const int arow = row0 + bM;
      const int nb = arow >> 10, s0 = arow & 1023;
      const int h = ((bN & 1023) >> 6) + (d >> 6);
      u16* vout = Vt + (u64)(nb * NH + h) * SEQ * DKH +
                  (u64)(d & 63) * SEQ + s0 + sq;
#pragma unroll
      for (int c = 0; c < 8; c++) {
        const int sc = sq + c * 8;
        const int scs = sc ^ ((d & 7) << 3);
        *(uint4*)(vout + c * 8) = *(const uint4*)(&ldt[d * 256 + scs]);
      }
    }
  } else {
#pragma unroll
    for (int n = 0; n < 4; n++) {
      int col = bN + wc * 64 + n * 16 + l15;
      float bv = bias[col];
#pragma unroll
      for (int mt = 0; mt < 4; mt++) {
#pragma unroll
        for (int r = 0; r < 4; r++) {
          int row = bM + wr * 64 + mt * 16 + l4 * 4 + r;
          outf[(u64)row * EMB + col] = acc[mt][n][r] + bv;
        }
      }
    }
  }
}

__global__ __launch_bounds__(512, 2) void gemm_qkv(
    const u16* __restrict__ X, const u16* __restrict__ Wt,
    const float* __restrict__ bias,
    u16* __restrict__ Qg, u16* __restrict__ Kg, u16* __restrict__ Vt,
    int row0) {
  gemm_core<0>(X, Wt, bias, Qg, Kg, Vt, nullptr, row0);
}

__global__ __launch_bounds__(512, 2) void gemm_out(
    const u16* __restrict__ X, const u16* __restrict__ Wt,
    const float* __restrict__ bias, float* __restrict__ out) {
  gemm_core<1>(X, Wt, bias, nullptr, nullptr, nullptr, out, 0);
}

// ---------- MFMA flash attention (unchanged from round 6) ----------
__global__ __launch_bounds__(512, 4) void attn_mfma(
    const u16* __restrict__ Q, const u16* __restrict__ K,
    const u16* __restrict__ Vt, const u32* __restrict__ maskbits,
    int b0, u16* __restrict__ ctx) {
  __shared__ __align__(16) u16 Ks[2][64 * 64];
  __shared__ __align__(16) u16 Vs[64 * 64];
  __shared__ __align__(16) u16 Ps[256 * 64];

  const int t = threadIdx.x;
  const int lane = t & 63, w = t >> 6;
  const int l15 = lane & 15, l4 = lane >> 4;
  const int bid = blockIdx.x;
  const int h = bid & 15;
  const int qt = (bid >> 4) & 3;
  const int n = bid >> 6;
  const int nh = n * NH + h;
  const int q0 = qt * 256;
  const u64 hoff = (u64)nh * SEQ * DKH;

  const int r7 = l15 & 7;
  const int cA = (l4 ^ r7) << 3;
  const int cB = (l4 ^ r7 ^ 4) << 3;

  const int rt = w * 8 + (lane >> 3);
  const int chk = ((lane & 7) ^ (lane >> 3)) << 3;
  const u16* Kp = K + hoff + (u64)rt * DKH + chk;
  const u16* Vp = Vt + hoff + (u64)rt * SEQ + chk;
  const int ldsO = w * 512;

  short8 qf[2][2];
  {
    const u16* qpA = Q + hoff + (u64)(q0 + w * 32 + l15) * DKH + l4 * 8;
    qf[0][0] = *(const short8*)(qpA);
    qf[0][1] = *(const short8*)(qpA + 32);
    const u16* qpB = qpA + 16 * DKH;
    qf[1][0] = *(const short8*)(qpB);
    qf[1][1] = *(const short8*)(qpB + 32);
  }

  short8 ones;
#pragma unroll
  for (int e = 0; e < 8; e++) ones[e] = (short)0x3F80;

  floatx4 o[2][4];
#pragma unroll
  for (int s = 0; s < 2; s++)
#pragma unroll
    for (int j = 0; j < 4; j++) o[s][j] = (floatx4){0.f, 0.f, 0.f, 0.f};
  floatx4 osum[2];
  osum[0] = (floatx4){0.f, 0.f, 0.f, 0.f};
  osum[1] = (floatx4){0.f, 0.f, 0.f, 0.f};

  const u64 mrow0 = ((u64)((b0 + n) * SEQ + q0 + w * 32 + l15)) * 32;
  const u64 mrow1 = mrow0 + 16 * 32;
  const int pq0 = w * 32 + l15;
  const int pq1 = pq0 + 16;
  const int pc0 = (l4 * 4) ^ (r7 << 3);

  glds16(Kp, &Ks[0][ldsO]);
  glds16(Vp, &Vs[ldsO]);
  __syncthreads();

  int cur = 0;
  for (int kc = 0; kc < SEQ; kc += 64) {
    if (kc > 0) glds16(Vp + kc, &Vs[ldsO]);
    const int havek = (kc + 64 < SEQ);
    if (havek) glds16(Kp + (kc + 64) * DKH, &Ks[cur ^ 1][ldsO]);

    const u64 mb0 = *(const u64*)(maskbits + mrow0 + (kc >> 5));
    const u64 mb1 = *(const u64*)(maskbits + mrow1 + (kc >> 5));
    const u16* Kc = &Ks[cur][0];

    __builtin_amdgcn_s_setprio(1);
#pragma unroll
    for (int j = 0; j < 4; j++) {
      const int rb = (j * 16 + l15) * 64;
      short8 kb0 = *(const short8*)(&Kc[rb + cA]);
      short8 kb1 = *(const short8*)(&Kc[rb + cB]);
      floatx4 s0 = (floatx4){0.f, 0.f, 0.f, 0.f};
      floatx4 s1 = (floatx4){0.f, 0.f, 0.f, 0.f};
      s0 = __builtin_amdgcn_mfma_f32_16x16x32_bf16(kb0, qf[0][0], s0, 0, 0, 0);
      s0 = __builtin_amdgcn_mfma_f32_16x16x32_bf16(kb1, qf[0][1], s0, 0, 0, 0);
      s1 = __builtin_amdgcn_mfma_f32_16x16x32_bf16(kb0, qf[1][0], s1, 0, 0, 0);
      s1 = __builtin_amdgcn_mfma_f32_16x16x32_bf16(kb1, qf[1][1], s1, 0, 0, 0);

      const u32 mj0 = (u32)(mb0 >> (j * 16 + l4 * 4));
      const u32 mj1 = (u32)(mb1 >> (j * 16 + l4 * 4));
      float p00 = __uint_as_float(
          __float_as_uint(__builtin_amdgcn_exp2f(s0[0])) &
          (u32)__builtin_amdgcn_sbfe(mj0, 0, 1));
      float p01 = __uint_as_float(
          __float_as_uint(__builtin_amdgcn_exp2f(s0[1])) &
          (u32)__builtin_amdgcn_sbfe(mj0, 1, 1));
      float p02 = __uint_as_float(
          __float_as_uint(__builtin_amdgcn_exp2f(s0[2])) &
          (u32)__builtin_amdgcn_sbfe(mj0, 2, 1));
      float p03 = __uint_as_float(
          __float_as_uint(__builtin_amdgcn_exp2f(s0[3])) &
          (u32)__builtin_amdgcn_sbfe(mj0, 3, 1));
      float p10 = __uint_as_float(
          __float_as_uint(__builtin_amdgcn_exp2f(s1[0])) &
          (u32)__builtin_amdgcn_sbfe(mj1, 0, 1));
      float p11 = __uint_as_float(
          __float_as_uint(__builtin_amdgcn_exp2f(s1[1])) &
          (u32)__builtin_amdgcn_sbfe(mj1, 1, 1));
      float p12 = __uint_as_float(
          __float_as_uint(__builtin_amdgcn_exp2f(s1[2])) &
          (u32)__builtin_amdgcn_sbfe(mj1, 2, 1));
      float p13 = __uint_as_float(
          __float_as_uint(__builtin_amdgcn_exp2f(s1[3])) &
          (u32)__builtin_amdgcn_sbfe(mj1, 3, 1));

      uint2 pk0, pk1;
      asm("v_cvt_pk_bf16_f32 %0, %1, %2" : "=v"(pk0.x) : "v"(p00), "v"(p01));
      asm("v_cvt_pk_bf16_f32 %0, %1, %2" : "=v"(pk0.y) : "v"(p02), "v"(p03));
      asm("v_cvt_pk_bf16_f32 %0, %1, %2" : "=v"(pk1.x) : "v"(p10), "v"(p11));
      asm("v_cvt_pk_bf16_f32 %0, %1, %2" : "=v"(pk1.y) : "v"(p12), "v"(p13));
      const int pcol = (j * 16) ^ pc0;
      *(uint2*)(&Ps[pq0 * 64 + pcol]) = pk0;
      *(uint2*)(&Ps[pq1 * 64 + pcol]) = pk1;
    }

    if (havek) asm volatile("s_waitcnt vmcnt(1)" ::: "memory");
    else       asm volatile("s_waitcnt vmcnt(0)" ::: "memory");
    __builtin_amdgcn_s_barrier();

    short8 pa[2][2];
    pa[0][0] = *(const short8*)(&Ps[pq0 * 64 + cA]);
    pa[0][1] = *(const short8*)(&Ps[pq0 * 64 + cB]);
    pa[1][0] = *(const short8*)(&Ps[pq1 * 64 + cA]);
    pa[1][1] = *(const short8*)(&Ps[pq1 * 64 + cB]);
#pragma unroll
    for (int j = 0; j < 4; j++) {
      const int rb = (j * 16 + l15) * 64;
      short8 vb0 = *(const short8*)(&Vs[rb + cA]);
      short8 vb1 = *(const short8*)(&Vs[rb + cB]);
      o[0][j] = __builtin_amdgcn_mfma_f32_16x16x32_bf16(pa[0][0], vb0, o[0][j], 0, 0, 0);
      o[0][j] = __builtin_amdgcn_mfma_f32_16x16x32_bf16(pa[0][1], vb1, o[0][j], 0, 0, 0);
      o[1][j] = __builtin_amdgcn_mfma_f32_16x16x32_bf16(pa[1][0], vb0, o[1][j], 0, 0, 0);
      o[1][j] = __builtin_amdgcn_mfma_f32_16x16x32_bf16(pa[1][1], vb1, o[1][j], 0, 0, 0);
    }
    osum[0] = __builtin_amdgcn_mfma_f32_16x16x32_bf16(pa[0][0], ones, osum[0], 0, 0, 0);
    osum[0] = __builtin_amdgcn_mfma_f32_16x16x32_bf16(pa[0][1], ones, osum[0], 0, 0, 0);
    osum[1] = __builtin_amdgcn_mfma_f32_16x16x32_bf16(pa[1][0], ones, osum[1], 0, 0, 0);
    osum[1] = __builtin_amdgcn_mfma_f32_16x16x32_bf16(pa[1][1], ones, osum[1], 0, 0, 0);
    __builtin_amdgcn_s_setprio(0);

    __syncthreads();
    cur ^= 1;
  }

#pragma unroll
  for (int s = 0; s < 2; s++) {
#pragma unroll
    for (int r = 0; r < 4; r++) {
      float invr = 1.0f / fmaxf(osum[s][r], 1e-30f);
      int q = q0 + w * 32 + s * 16 + l4 * 4 + r;
      u64 base = ((u64)(n * SEQ + q)) * EMB + h * DKH + l15;
#pragma unroll
      for (int j = 0; j < 4; j++)
        ctx[base + j * 16] = f2b(o[s][j][r] * invr);
    }
  }
}

extern "C" void kernel_launch(void* const* d_in, const int* in_sizes, int n_in,
                              void* d_out, int out_size, void* d_ws, size_t ws_size,
                              hipStream_t stream) {
  int bigI[2] = {0, 1}, wI[4] = {2, 4, 6, 8}, bI[4] = {3, 5, 7, 9};
  int nb = 0, nw = 0, nbi = 0;
  for (int i = 0; i < n_in; i++) {
    if (in_sizes[i] == 8388608) { if (nb < 2) bigI[nb++] = i; }
    else if (in_sizes[i] == 1048576) { if (nw < 4) wI[nw++] = i; }
    else if (in_sizes[i] == 1024) { if (nbi < 4) bI[nbi++] = i; }
  }
  int oq = 0, ok = 1, ov = 2, oo = 3;
  if (nb == 2 && bigI[0] == 4 && bigI[1] == 9) { oq = 2; ok = 0; ov = 3; oo = 1; }

  const void* bigA = d_in[bigI[0]];
  const void* bigB = d_in[bigI[1]];
  const void* Wq = d_in[wI[oq]];
  const void* Wk = d_in[wI[ok]];
  const void* Wv = d_in[wI[ov]];
  const void* Wo = d_in[wI[oo]];
  const void* bq = d_in[bI[oq]];
  const void* bk = d_in[bI[ok]];
  const void* bv = d_in[bI[ov]];
  const void* bo = d_in[bI[oo]];

  char* ws = (char*)d_ws;
  u16* WtQKV = (u16*)ws;
  u16* WtO   = (u16*)(ws + (6ull << 20));
  float* biasf = (float*)(ws + (8ull << 20));
  int* flags = (int*)(ws + (8ull << 20) + 16384);
  u32* maskbits = (u32*)(ws + (8ull << 20) + 65536);
  u16* xb = (u16*)(ws + (10ull << 20));
  char* grp = ws + (26ull << 20);

  int G = 1;
  for (int g = 8; g >= 1; g >>= 1) {
    if (ws_size >= (26ull << 20) + (u64)g * (8ull << 20)) { G = g; break; }
  }
  const u64 gsz = (u64)G * (2ull << 20);
  u16* Qg = (u16*)grp;
  u16* Kg = (u16*)(grp + gsz);
  u16* ctx = (u16*)(grp + 2 * gsz);
  u16* Vt = (u16*)(grp + 3 * gsz);

  dim3 tb(256);

  probe_inputs<<<dim3(1), tb, 0, stream>>>((const u32*)bigA, (const u32*)bigB, flags);

  // fused preprocessing: 8192 convert_x + 1024 maskbits + 4096 w4 + 4 biases
  preprocess<<<dim3(13316), tb, 0, stream>>>(
      bigA, bigB, flags, xb, maskbits,
      Wq, Wk, Wv, Wo, WtQKV, WtO,
      bq, bk, bv, bo, biasf);

  for (int b0 = 0; b0 < 8; b0 += G) {
    int row0 = b0 * 1024;
    gemm_qkv<<<dim3(4 * G, 24), dim3(512), 0, stream>>>(xb, WtQKV, biasf, Qg, Kg, Vt, row0);

    attn_mfma<<<dim3(G * 16 * 4), dim3(512), 0, stream>>>(Qg, Kg, Vt, maskbits, b0, ctx);

    gemm_out<<<dim3(4 * G, 8), dim3(512), 0, stream>>>(ctx, WtO, biasf + 3072,
                                                       (float*)d_out + (u64)row0 * EMB);
  }
}

// Round 10
// 291.249 us; speedup vs baseline: 1.1016x; 1.1016x over previous
//
#include <hip/hip_runtime.h>
#include <hip/hip_bf16.h>

typedef unsigned short u16;
typedef unsigned int   u32;
typedef unsigned long long u64;

#define SEQ 1024
#define EMB 1024
#define NH  16
#define DKH 64

// 0.125 (1/sqrt(64)) * log2(e): folded into Wq/bq so attn uses exp2 directly
#define QSCALE 0.18033688f

typedef __attribute__((ext_vector_type(8))) short short8;
typedef __attribute__((ext_vector_type(4))) float floatx4;

__device__ __forceinline__ float b2f(u16 u) {
  return __uint_as_float(((u32)u) << 16);
}
__device__ __forceinline__ u16 f2b(float f) {
  u32 u = __float_as_uint(f);
  u32 r = u + 0x7fffu + ((u >> 16) & 1u);   // RNE
  return (u16)(r >> 16);
}

// async global->LDS, 16 B per lane; LDS dst = wave-uniform base + lane*16
__device__ __forceinline__ void glds16(const u16* g, u16* l) {
  __builtin_amdgcn_global_load_lds(
      (const __attribute__((address_space(1))) u32*)g,
      (__attribute__((address_space(3))) u32*)l, 16, 0, 0);
}

// ---------- probe the two 8M-element buffers ----------
// flags[0]=xIsB, flags[1]=x storage (1=bf16,0=fp32), flags[2]=mask bytes (1) vs int32 (0)
__global__ __launch_bounds__(256) void probe_inputs(const u32* __restrict__ A,
                                                    const u32* __restrict__ B,
                                                    int* __restrict__ flags) {
  __shared__ int mA, mB, mBig, xB16;
  if (threadIdx.x == 0) { mA = 0; mB = 0; mBig = 0; xB16 = 0; }
  __syncthreads();
  int la = 0, lb = 0;
  for (int i = threadIdx.x; i < 4096; i += 256) {
    if ((A[i] & 0xFEFEFEFEu) == 0) la++;
    if ((B[i] & 0xFEFEFEFEu) == 0) lb++;
  }
  atomicAdd(&mA, la); atomicAdd(&mB, lb);
  __syncthreads();
  const int xIsB = (mA > mB) ? 1 : 0;
  const u32* X = xIsB ? B : A;
  const u32* M = xIsB ? A : B;
  int big = 0, cnt = 0;
  for (int i = threadIdx.x; i < 4096; i += 256)
    if (M[i] > 1u) big = 1;
  for (int i = threadIdx.x; i < 2048; i += 256) {
    u16 v = (u16)(X[i] & 0xffffu);
    int e = (v >> 7) & 0xFF;
    if (e >= 110 && e <= 135) cnt++;
  }
  if (big) atomicOr(&mBig, 1);
  atomicAdd(&xB16, cnt);
  __syncthreads();
  if (threadIdx.x == 0) {
    flags[0] = xIsB;
    flags[1] = (xB16 > 1500) ? 1 : 0;
    flags[2] = mBig;
  }
}

// ============================================================================
// Fused preprocessing: ONE dispatch replaces convert_x + build_maskbits +
// transpose_convert_w4 + convert_biases (all independent given flags).
// ============================================================================
__global__ __launch_bounds__(256) void preprocess(
    const void* __restrict__ bigA, const void* __restrict__ bigB,
    const int* __restrict__ flags,
    u16* __restrict__ xb, u32* __restrict__ maskbits,
    const void* __restrict__ w0, const void* __restrict__ w1,
    const void* __restrict__ w2, const void* __restrict__ w3,
    u16* __restrict__ outQKV, u16* __restrict__ outO,
    const void* __restrict__ b0, const void* __restrict__ b1,
    const void* __restrict__ b2, const void* __restrict__ b3,
    float* __restrict__ biasf) {
  __shared__ float tile[32][33];
  const int bidg = blockIdx.x;
  const int t = threadIdx.x;
  const int amode = flags[1];

  if (bidg < 8192) {
    const void* x = flags[0] ? bigB : bigA;
    int i = (bidg * 256 + t) * 4;
    if (amode) {
      *(ushort4*)(xb + i) = *(const ushort4*)((const u16*)x + i);
    } else {
      float4 v = *(const float4*)((const float*)x + i);
      ushort4 o;
      o.x = f2b(v.x); o.y = f2b(v.y); o.z = f2b(v.z); o.w = f2b(v.w);
      *(ushort4*)(xb + i) = o;
    }
  } else if (bidg < 9216) {
    const void* mask = flags[0] ? bigA : bigB;
    const int mbyte = flags[2];
    const int lane = t & 63, wv = t >> 6;
    const u64 base0 = (u64)(bidg - 8192) * 8192;
#pragma unroll 4
    for (int k = 0; k < 32; k++) {
      u64 idx = base0 + k * 256 + t;
      int v;
      if (mbyte) v = ((const unsigned char*)mask)[idx] == 0;
      else       v = ((const u32*)mask)[idx] == 0;
      u64 b = __ballot(v);
      if (lane == 0) {
        u64 wbase = (base0 + k * 256 + wv * 64) >> 5;
        maskbits[wbase]     = (u32)b;
        maskbits[wbase + 1] = (u32)(b >> 32);
      }
    }
  } else if (bidg < 13312) {
    const int idx = bidg - 9216;
    const int z = idx >> 10;
    const int byi = (idx & 1023) >> 5;
    const int bxi = idx & 31;
    const void* in = (z == 0) ? w0 : (z == 1) ? w1 : (z == 2) ? w2 : w3;
    u16* out = (z < 3) ? (outQKV + (u64)z * EMB * EMB) : outO;
    const float scale = (z == 0) ? QSCALE : 1.0f;
    const int tx = t & 31;
    const int ty = t >> 5;
    const int bx = bxi * 32, by = byi * 32;
    if (amode) {
      const u16* inb = (const u16*)in;
#pragma unroll
      for (int r = ty; r < 32; r += 8)
        tile[r][tx] = b2f(inb[(u64)(by + r) * EMB + bx + tx]);
    } else {
      const float* inf = (const float*)in;
#pragma unroll
      for (int r = ty; r < 32; r += 8)
        tile[r][tx] = inf[(u64)(by + r) * EMB + bx + tx];
    }
    __syncthreads();
#pragma unroll
    for (int r = ty; r < 32; r += 8)
      out[(u64)(bx + r) * EMB + by + tx] = f2b(tile[tx][r] * scale);
  } else {
    const int widx = bidg - 13312;
    const void* ptrs[4] = {b0, b1, b2, b3};
    const void* p = ptrs[widx];
    const float scale = (widx == 0) ? QSCALE : 1.0f;
    for (int i = t; i < 1024; i += 256) {
      float v = amode ? b2f(((const u16*)p)[i]) : ((const float*)p)[i];
      biasf[widx * 1024 + i] = v * scale;
    }
  }
}

// ============================================================================
// GEMM (round-6 proven core, default blockIdx mapping — the x-major
// round-robin already gives each XCD a 4-Apanel x 8-Bpanel working set that
// L2-fits; round-9's chunked swizzle quadrupled FETCH and is reverted).
// 256x128 tile, BK=64, 8 waves, double-buffered LDS (96 KB), counted
// vmcnt(6) + raw s_barrier (T3-lite), setprio (T5), XOR-swizzled LDS via
// inverse-swizzled global_load_lds source (T2/m173).
// Epilogues: Q/K staged through LDS for contiguous 16B stores (NEW);
// V -> Vt via LDS transpose; fp32 linear for gemm_out.
// ============================================================================

// epilogue mode 0: QKV (Q/K head-scatter u16, V transposed [d][s]); 1: fp32
template <int OUTMODE>
__device__ __forceinline__ void gemm_core(
    const u16* __restrict__ X, const u16* __restrict__ Wt,
    const float* __restrict__ bias,
    u16* __restrict__ Qg, u16* __restrict__ Kg, u16* __restrict__ Vt,
    float* __restrict__ outf, int row0) {
  __shared__ __align__(16) u16 lds[2][(256 + 128) * 64];
  const int t = threadIdx.x;
  const int lane = t & 63;
  const int w = t >> 6;                 // 0..7
  const int wr = w >> 1, wc = w & 1;    // wave tile: rows wr*64, cols wc*64
  const int l15 = lane & 15, l4 = lane >> 4;
  const int bM = blockIdx.x * 256, bN = blockIdx.y * 128;
  const int r7 = l15 & 7;
  const int cA = (l4 ^ r7) << 3;        // swizzled chunk for k-half 0
  const int cB = (l4 ^ r7 ^ 4) << 3;    // swizzled chunk for k-half 1

  floatx4 acc[4][4];
#pragma unroll
  for (int i = 0; i < 4; i++)
#pragma unroll
    for (int j = 0; j < 4; j++)
      acc[i][j] = (floatx4){0.f, 0.f, 0.f, 0.f};

  // staging: round covers 64 rows; wave w rows w*8+(lane>>3); chunk lane&7,
  // inverse-swizzled at the global source (LDS dst stays linear).
  const int srow = w * 8 + (lane >> 3);
  const int schk = ((lane & 7) ^ (lane >> 3)) << 3;
  const u16* Ap = X + (u64)(row0 + bM + srow) * EMB + schk;
  const u16* Bp = Wt + (u64)(bN + srow) * EMB + schk;
  u16* Ad0 = &lds[0][w * 512];
  u16* Bd0 = &lds[0][16384 + w * 512];
  u16* Ad1 = &lds[1][w * 512];
  u16* Bd1 = &lds[1][16384 + w * 512];

  auto stage = [&](u16* Ad, u16* Bd, int k0) {
    glds16(Ap + k0, Ad);
    glds16(Ap + k0 + 64 * EMB, Ad + 4096);
    glds16(Ap + k0 + 128 * EMB, Ad + 8192);
    glds16(Ap + k0 + 192 * EMB, Ad + 12288);
    glds16(Bp + k0, Bd);
    glds16(Bp + k0 + 64 * EMB, Bd + 4096);
  };

  auto compute = [&](const u16* __restrict__ Ab, const u16* __restrict__ Bb) {
    short8 bfr[4][2];
#pragma unroll
    for (int n = 0; n < 4; n++) {
      const int gr = (wc * 64 + n * 16 + l15) * 64;
      bfr[n][0] = *(const short8*)(&Bb[gr + cA]);
      bfr[n][1] = *(const short8*)(&Bb[gr + cB]);
    }
#pragma unroll
    for (int mh = 0; mh < 2; mh++) {
      short8 af2[2][2];
#pragma unroll
      for (int m = 0; m < 2; m++) {
        const int fr = (wr * 64 + mh * 32 + m * 16 + l15) * 64;
        af2[m][0] = *(const short8*)(&Ab[fr + cA]);
        af2[m][1] = *(const short8*)(&Ab[fr + cB]);
      }
      __builtin_amdgcn_s_setprio(1);
#pragma unroll
      for (int m = 0; m < 2; m++)
#pragma unroll
        for (int n = 0; n < 4; n++) {
          acc[mh * 2 + m][n] = __builtin_amdgcn_mfma_f32_16x16x32_bf16(
              af2[m][0], bfr[n][0], acc[mh * 2 + m][n], 0, 0, 0);
          acc[mh * 2 + m][n] = __builtin_amdgcn_mfma_f32_16x16x32_bf16(
              af2[m][1], bfr[n][1], acc[mh * 2 + m][n], 0, 0, 0);
        }
      __builtin_amdgcn_s_setprio(0);
    }
  };

  stage(Ad0, Bd0, 0);
  // 16 K-tiles, 2 per unrolled step; counted vmcnt keeps next tile in flight
  for (int k0 = 0; k0 < EMB; k0 += 128) {
    stage(Ad1, Bd1, k0 + 64);
    asm volatile("s_waitcnt vmcnt(6)" ::: "memory");
    asm volatile("s_barrier" ::: "memory");
    compute(&lds[0][0], &lds[0][16384]);
    asm volatile("s_barrier" ::: "memory");
    if (k0 + 128 < EMB) {
      stage(Ad0, Bd0, k0 + 128);
      asm volatile("s_waitcnt vmcnt(6)" ::: "memory");
    } else {
      asm volatile("s_waitcnt vmcnt(0)" ::: "memory");
    }
    asm volatile("s_barrier" ::: "memory");
    compute(&lds[1][0], &lds[1][16384]);
    asm volatile("s_barrier" ::: "memory");
  }

  if (OUTMODE == 0) {
    const int sec = bN >> 10;               // 0=Q,1=K,2=V (block-uniform)
    const int nb = bM >> 10;                // group-local batch
    if (sec < 2) {
      // Q/K: stage [s_local][d_local] in LDS ([256][136] u16, +8 pad keeps
      // 16B row alignment and breaks bank alignment), then write each
      // head's contiguous [s][d] region with full 16B/lane stores.
      u16* outp = (sec == 0) ? Qg : Kg;
      u16* ldt = &lds[0][0];                // 69632 B of the 96 KB block
#pragma unroll
      for (int n = 0; n < 4; n++) {
        const int cl = wc * 64 + n * 16 + l15;          // 0..127
        const float bv = bias[bN + cl];
#pragma unroll
        for (int mt = 0; mt < 4; mt++) {
#pragma unroll
          for (int r = 0; r < 4; r++) {
            const int rl = wr * 64 + mt * 16 + l4 * 4 + r;
            ldt[rl * 136 + cl] = f2b(acc[mt][n][r] + bv);
          }
        }
      }
      __syncthreads();
      const int h0 = (bN & 1023) >> 6;
      const int s0 = bM & 1023;
#pragma unroll
      for (int hh = 0; hh < 2; hh++) {
        u16* basep = outp + ((u64)(nb * NH + h0 + hh) * SEQ + s0) * DKH;
#pragma unroll
        for (int kk = 0; kk < 4; kk++) {
          const int ci = t + 512 * kk;      // 0..2047 chunks of 8 elems
          const int s = ci >> 3, d0 = (ci & 7) * 8;
          *(uint4*)(basep + s * 64 + d0) =
              *(const uint4*)(&ldt[s * 136 + hh * 64 + d0]);
        }
      }
    } else {
      // V section: transpose through LDS, write Vt[d][s] coalesced.
      u16* ldt = &lds[0][0];                // 64 KB of the 96 KB block
#pragma unroll
      for (int n = 0; n < 4; n++) {
        const int dl = wc * 64 + n * 16 + l15;          // 0..127
        const float bv = bias[bN + dl];
#pragma unroll
        for (int mt = 0; mt < 4; mt++) {
          const int sb = wr * 64 + mt * 16 + l4 * 4;    // mult of 4
          const int sp = sb ^ ((dl & 7) << 3);          // stays 4-aligned
          u32 w0 = (u32)f2b(acc[mt][n][0] + bv) |
                   ((u32)f2b(acc[mt][n][1] + bv) << 16);
          u32 w1 = (u32)f2b(acc[mt][n][2] + bv) |
                   ((u32)f2b(acc[mt][n][3] + bv) << 16);
          *(u32*)(&ldt[dl * 256 + sp])     = w0;
          *(u32*)(&ldt[dl * 256 + sp + 2]) = w1;
        }
      }
      __syncthreads();
      const int d  = t >> 2;          // 0..127
      const int sq = (t & 3) * 64;    // s quarter
      const int s0 = bM & 1023;
      const int h = ((bN & 1023) >> 6) + (d >> 6);
      u16* vout = Vt + (u64)(nb * NH + h) * SEQ * DKH +
                  (u64)(d & 63) * SEQ + s0 + sq;
#pragma unroll
      for (int c = 0; c < 8; c++) {
        const int sc = sq + c * 8;
        const int scs = sc ^ ((d & 7) << 3);
        *(uint4*)(vout + c * 8) = *(const uint4*)(&ldt[d * 256 + scs]);
      }
    }
  } else {
#pragma unroll
    for (int n = 0; n < 4; n++) {
      int col = bN + wc * 64 + n * 16 + l15;
      float bv = bias[col];
#pragma unroll
      for (int mt = 0; mt < 4; mt++) {
#pragma unroll
        for (int r = 0; r < 4; r++) {
          int row = bM + wr * 64 + mt * 16 + l4 * 4 + r;
          outf[(u64)row * EMB + col] = acc[mt][n][r] + bv;
        }
      }
    }
  }
}

__global__ __launch_bounds__(512, 2) void gemm_qkv(
    const u16* __restrict__ X, const u16* __restrict__ Wt,
    const float* __restrict__ bias,
    u16* __restrict__ Qg, u16* __restrict__ Kg, u16* __restrict__ Vt,
    int row0) {
  gemm_core<0>(X, Wt, bias, Qg, Kg, Vt, nullptr, row0);
}

__global__ __launch_bounds__(512, 2) void gemm_out(
    const u16* __restrict__ X, const u16* __restrict__ Wt,
    const float* __restrict__ bias, float* __restrict__ out) {
  gemm_core<1>(X, Wt, bias, nullptr, nullptr, nullptr, out, 0);
}

// ---------- MFMA flash attention (unchanged from round 6) ----------
__global__ __launch_bounds__(512, 4) void attn_mfma(
    const u16* __restrict__ Q, const u16* __restrict__ K,
    const u16* __restrict__ Vt, const u32* __restrict__ maskbits,
    int b0, u16* __restrict__ ctx) {
  __shared__ __align__(16) u16 Ks[2][64 * 64];
  __shared__ __align__(16) u16 Vs[64 * 64];
  __shared__ __align__(16) u16 Ps[256 * 64];

  const int t = threadIdx.x;
  const int lane = t & 63, w = t >> 6;
  const int l15 = lane & 15, l4 = lane >> 4;
  const int bid = blockIdx.x;
  const int h = bid & 15;
  const int qt = (bid >> 4) & 3;
  const int n = bid >> 6;
  const int nh = n * NH + h;
  const int q0 = qt * 256;
  const u64 hoff = (u64)nh * SEQ * DKH;

  const int r7 = l15 & 7;
  const int cA = (l4 ^ r7) << 3;
  const int cB = (l4 ^ r7 ^ 4) << 3;

  const int rt = w * 8 + (lane >> 3);
  const int chk = ((lane & 7) ^ (lane >> 3)) << 3;
  const u16* Kp = K + hoff + (u64)rt * DKH + chk;
  const u16* Vp = Vt + hoff + (u64)rt * SEQ + chk;
  const int ldsO = w * 512;

  short8 qf[2][2];
  {
    const u16* qpA = Q + hoff + (u64)(q0 + w * 32 + l15) * DKH + l4 * 8;
    qf[0][0] = *(const short8*)(qpA);
    qf[0][1] = *(const short8*)(qpA + 32);
    const u16* qpB = qpA + 16 * DKH;
    qf[1][0] = *(const short8*)(qpB);
    qf[1][1] = *(const short8*)(qpB + 32);
  }

  short8 ones;
#pragma unroll
  for (int e = 0; e < 8; e++) ones[e] = (short)0x3F80;

  floatx4 o[2][4];
#pragma unroll
  for (int s = 0; s < 2; s++)
#pragma unroll
    for (int j = 0; j < 4; j++) o[s][j] = (floatx4){0.f, 0.f, 0.f, 0.f};
  floatx4 osum[2];
  osum[0] = (floatx4){0.f, 0.f, 0.f, 0.f};
  osum[1] = (floatx4){0.f, 0.f, 0.f, 0.f};

  const u64 mrow0 = ((u64)((b0 + n) * SEQ + q0 + w * 32 + l15)) * 32;
  const u64 mrow1 = mrow0 + 16 * 32;
  const int pq0 = w * 32 + l15;
  const int pq1 = pq0 + 16;
  const int pc0 = (l4 * 4) ^ (r7 << 3);

  glds16(Kp, &Ks[0][ldsO]);
  glds16(Vp, &Vs[ldsO]);
  __syncthreads();

  int cur = 0;
  for (int kc = 0; kc < SEQ; kc += 64) {
    if (kc > 0) glds16(Vp + kc, &Vs[ldsO]);
    const int havek = (kc + 64 < SEQ);
    if (havek) glds16(Kp + (kc + 64) * DKH, &Ks[cur ^ 1][ldsO]);

    const u64 mb0 = *(const u64*)(maskbits + mrow0 + (kc >> 5));
    const u64 mb1 = *(const u64*)(maskbits + mrow1 + (kc >> 5));
    const u16* Kc = &Ks[cur][0];

    __builtin_amdgcn_s_setprio(1);
#pragma unroll
    for (int j = 0; j < 4; j++) {
      const int rb = (j * 16 + l15) * 64;
      short8 kb0 = *(const short8*)(&Kc[rb + cA]);
      short8 kb1 = *(const short8*)(&Kc[rb + cB]);
      floatx4 s0 = (floatx4){0.f, 0.f, 0.f, 0.f};
      floatx4 s1 = (floatx4){0.f, 0.f, 0.f, 0.f};
      s0 = __builtin_amdgcn_mfma_f32_16x16x32_bf16(kb0, qf[0][0], s0, 0, 0, 0);
      s0 = __builtin_amdgcn_mfma_f32_16x16x32_bf16(kb1, qf[0][1], s0, 0, 0, 0);
      s1 = __builtin_amdgcn_mfma_f32_16x16x32_bf16(kb0, qf[1][0], s1, 0, 0, 0);
      s1 = __builtin_amdgcn_mfma_f32_16x16x32_bf16(kb1, qf[1][1], s1, 0, 0, 0);

      const u32 mj0 = (u32)(mb0 >> (j * 16 + l4 * 4));
      const u32 mj1 = (u32)(mb1 >> (j * 16 + l4 * 4));
      float p00 = __uint_as_float(
          __float_as_uint(__builtin_amdgcn_exp2f(s0[0])) &
          (u32)__builtin_amdgcn_sbfe(mj0, 0, 1));
      float p01 = __uint_as_float(
          __float_as_uint(__builtin_amdgcn_exp2f(s0[1])) &
          (u32)__builtin_amdgcn_sbfe(mj0, 1, 1));
      float p02 = __uint_as_float(
          __float_as_uint(__builtin_amdgcn_exp2f(s0[2])) &
          (u32)__builtin_amdgcn_sbfe(mj0, 2, 1));
      float p03 = __uint_as_float(
          __float_as_uint(__builtin_amdgcn_exp2f(s0[3])) &
          (u32)__builtin_amdgcn_sbfe(mj0, 3, 1));
      float p10 = __uint_as_float(
          __float_as_uint(__builtin_amdgcn_exp2f(s1[0])) &
          (u32)__builtin_amdgcn_sbfe(mj1, 0, 1));
      float p11 = __uint_as_float(
          __float_as_uint(__builtin_amdgcn_exp2f(s1[1])) &
          (u32)__builtin_amdgcn_sbfe(mj1, 1, 1));
      float p12 = __uint_as_float(
          __float_as_uint(__builtin_amdgcn_exp2f(s1[2])) &
          (u32)__builtin_amdgcn_sbfe(mj1, 2, 1));
      float p13 = __uint_as_float(
          __float_as_uint(__builtin_amdgcn_exp2f(s1[3])) &
          (u32)__builtin_amdgcn_sbfe(mj1, 3, 1));

      uint2 pk0, pk1;
      asm("v_cvt_pk_bf16_f32 %0, %1, %2" : "=v"(pk0.x) : "v"(p00), "v"(p01));
      asm("v_cvt_pk_bf16_f32 %0, %1, %2" : "=v"(pk0.y) : "v"(p02), "v"(p03));
      asm("v_cvt_pk_bf16_f32 %0, %1, %2" : "=v"(pk1.x) : "v"(p10), "v"(p11));
      asm("v_cvt_pk_bf16_f32 %0, %1, %2" : "=v"(pk1.y) : "v"(p12), "v"(p13));
      const int pcol = (j * 16) ^ pc0;
      *(uint2*)(&Ps[pq0 * 64 + pcol]) = pk0;
      *(uint2*)(&Ps[pq1 * 64 + pcol]) = pk1;
    }

    if (havek) asm volatile("s_waitcnt vmcnt(1)" ::: "memory");
    else       asm volatile("s_waitcnt vmcnt(0)" ::: "memory");
    __builtin_amdgcn_s_barrier();

    short8 pa[2][2];
    pa[0][0] = *(const short8*)(&Ps[pq0 * 64 + cA]);
    pa[0][1] = *(const short8*)(&Ps[pq0 * 64 + cB]);
    pa[1][0] = *(const short8*)(&Ps[pq1 * 64 + cA]);
    pa[1][1] = *(const short8*)(&Ps[pq1 * 64 + cB]);
#pragma unroll
    for (int j = 0; j < 4; j++) {
      const int rb = (j * 16 + l15) * 64;
      short8 vb0 = *(const short8*)(&Vs[rb + cA]);
      short8 vb1 = *(const short8*)(&Vs[rb + cB]);
      o[0][j] = __builtin_amdgcn_mfma_f32_16x16x32_bf16(pa[0][0], vb0, o[0][j], 0, 0, 0);
      o[0][j] = __builtin_amdgcn_mfma_f32_16x16x32_bf16(pa[0][1], vb1, o[0][j], 0, 0, 0);
      o[1][j] = __builtin_amdgcn_mfma_f32_16x16x32_bf16(pa[1][0], vb0, o[1][j], 0, 0, 0);
      o[1][j] = __builtin_amdgcn_mfma_f32_16x16x32_bf16(pa[1][1], vb1, o[1][j], 0, 0, 0);
    }
    osum[0] = __builtin_amdgcn_mfma_f32_16x16x32_bf16(pa[0][0], ones, osum[0], 0, 0, 0);
    osum[0] = __builtin_amdgcn_mfma_f32_16x16x32_bf16(pa[0][1], ones, osum[0], 0, 0, 0);
    osum[1] = __builtin_amdgcn_mfma_f32_16x16x32_bf16(pa[1][0], ones, osum[1], 0, 0, 0);
    osum[1] = __builtin_amdgcn_mfma_f32_16x16x32_bf16(pa[1][1], ones, osum[1], 0, 0, 0);
    __builtin_amdgcn_s_setprio(0);

    __syncthreads();
    cur ^= 1;
  }

#pragma unroll
  for (int s = 0; s < 2; s++) {
#pragma unroll
    for (int r = 0; r < 4; r++) {
      float invr = 1.0f / fmaxf(osum[s][r], 1e-30f);
      int q = q0 + w * 32 + s * 16 + l4 * 4 + r;
      u64 base = ((u64)(n * SEQ + q)) * EMB + h * DKH + l15;
#pragma unroll
      for (int j = 0; j < 4; j++)
        ctx[base + j * 16] = f2b(o[s][j][r] * invr);
    }
  }
}

extern "C" void kernel_launch(void* const* d_in, const int* in_sizes, int n_in,
                              void* d_out, int out_size, void* d_ws, size_t ws_size,
                              hipStream_t stream) {
  int bigI[2] = {0, 1}, wI[4] = {2, 4, 6, 8}, bI[4] = {3, 5, 7, 9};
  int nb = 0, nw = 0, nbi = 0;
  for (int i = 0; i < n_in; i++) {
    if (in_sizes[i] == 8388608) { if (nb < 2) bigI[nb++] = i; }
    else if (in_sizes[i] == 1048576) { if (nw < 4) wI[nw++] = i; }
    else if (in_sizes[i] == 1024) { if (nbi < 4) bI[nbi++] = i; }
  }
  int oq = 0, ok = 1, ov = 2, oo = 3;
  if (nb == 2 && bigI[0] == 4 && bigI[1] == 9) { oq = 2; ok = 0; ov = 3; oo = 1; }

  const void* bigA = d_in[bigI[0]];
  const void* bigB = d_in[bigI[1]];
  const void* Wq = d_in[wI[oq]];
  const void* Wk = d_in[wI[ok]];
  const void* Wv = d_in[wI[ov]];
  const void* Wo = d_in[wI[oo]];
  const void* bq = d_in[bI[oq]];
  const void* bk = d_in[bI[ok]];
  const void* bv = d_in[bI[ov]];
  const void* bo = d_in[bI[oo]];

  char* ws = (char*)d_ws;
  u16* WtQKV = (u16*)ws;
  u16* WtO   = (u16*)(ws + (6ull << 20));
  float* biasf = (float*)(ws + (8ull << 20));
  int* flags = (int*)(ws + (8ull << 20) + 16384);
  u32* maskbits = (u32*)(ws + (8ull << 20) + 65536);
  u16* xb = (u16*)(ws + (10ull << 20));
  char* grp = ws + (26ull << 20);

  int G = 1;
  for (int g = 8; g >= 1; g >>= 1) {
    if (ws_size >= (26ull << 20) + (u64)g * (8ull << 20)) { G = g; break; }
  }
  const u64 gsz = (u64)G * (2ull << 20);
  u16* Qg = (u16*)grp;
  u16* Kg = (u16*)(grp + gsz);
  u16* ctx = (u16*)(grp + 2 * gsz);
  u16* Vt = (u16*)(grp + 3 * gsz);

  dim3 tb(256);

  probe_inputs<<<dim3(1), tb, 0, stream>>>((const u32*)bigA, (const u32*)bigB, flags);

  // fused preprocessing: 8192 convert_x + 1024 maskbits + 4096 w4 + 4 biases
  preprocess<<<dim3(13316), tb, 0, stream>>>(
      bigA, bigB, flags, xb, maskbits,
      Wq, Wk, Wv, Wo, WtQKV, WtO,
      bq, bk, bv, bo, biasf);

  for (int b0 = 0; b0 < 8; b0 += G) {
    int row0 = b0 * 1024;
    gemm_qkv<<<dim3(4 * G, 24), dim3(512), 0, stream>>>(xb, WtQKV, biasf, Qg, Kg, Vt, row0);

    attn_mfma<<<dim3(G * 16 * 4), dim3(512), 0, stream>>>(Qg, Kg, Vt, maskbits, b0, ctx);

    gemm_out<<<dim3(4 * G, 8), dim3(512), 0, stream>>>(ctx, WtO, biasf + 3072,
                                                       (float*)d_out + (u64)row0 * EMB);
  }
}

// Round 11
// 278.233 us; speedup vs baseline: 1.1531x; 1.0468x over previous
//
#include <hip/hip_runtime.h>
#include <hip/hip_bf16.h>

typedef unsigned short u16;
typedef unsigned int   u32;
typedef unsigned long long u64;

#define SEQ 1024
#define EMB 1024
#define NH  16
#define DKH 64

// 0.125 (1/sqrt(64)) * log2(e): folded into Wq/bq so attn uses exp2 directly
#define QSCALE 0.18033688f

typedef __attribute__((ext_vector_type(8))) short short8;
typedef __attribute__((ext_vector_type(4))) float floatx4;

__device__ __forceinline__ float b2f(u16 u) {
  return __uint_as_float(((u32)u) << 16);
}
__device__ __forceinline__ u16 f2b(float f) {
  u32 u = __float_as_uint(f);
  u32 r = u + 0x7fffu + ((u >> 16) & 1u);   // RNE
  return (u16)(r >> 16);
}

// async global->LDS, 16 B per lane; LDS dst = wave-uniform base + lane*16
__device__ __forceinline__ void glds16(const u16* g, u16* l) {
  __builtin_amdgcn_global_load_lds(
      (const __attribute__((address_space(1))) u32*)g,
      (__attribute__((address_space(3))) u32*)l, 16, 0, 0);
}

// ---------- probe the two 8M-element buffers ----------
// flags[0]=xIsB, flags[1]=x storage (1=bf16,0=fp32), flags[2]=mask bytes (1) vs int32 (0)
__global__ __launch_bounds__(256) void probe_inputs(const u32* __restrict__ A,
                                                    const u32* __restrict__ B,
                                                    int* __restrict__ flags) {
  __shared__ int mA, mB, mBig, xB16;
  if (threadIdx.x == 0) { mA = 0; mB = 0; mBig = 0; xB16 = 0; }
  __syncthreads();
  int la = 0, lb = 0;
  for (int i = threadIdx.x; i < 4096; i += 256) {
    if ((A[i] & 0xFEFEFEFEu) == 0) la++;
    if ((B[i] & 0xFEFEFEFEu) == 0) lb++;
  }
  atomicAdd(&mA, la); atomicAdd(&mB, lb);
  __syncthreads();
  const int xIsB = (mA > mB) ? 1 : 0;
  const u32* X = xIsB ? B : A;
  const u32* M = xIsB ? A : B;
  int big = 0, cnt = 0;
  for (int i = threadIdx.x; i < 4096; i += 256)
    if (M[i] > 1u) big = 1;
  for (int i = threadIdx.x; i < 2048; i += 256) {
    u16 v = (u16)(X[i] & 0xffffu);
    int e = (v >> 7) & 0xFF;
    if (e >= 110 && e <= 135) cnt++;
  }
  if (big) atomicOr(&mBig, 1);
  atomicAdd(&xB16, cnt);
  __syncthreads();
  if (threadIdx.x == 0) {
    flags[0] = xIsB;
    flags[1] = (xB16 > 1500) ? 1 : 0;
    flags[2] = mBig;
  }
}

// ============================================================================
// Fused preprocessing: ONE dispatch replaces convert_x + build_maskbits +
// transpose_convert_w4 + convert_biases (all independent given flags).
// ============================================================================
__global__ __launch_bounds__(256) void preprocess(
    const void* __restrict__ bigA, const void* __restrict__ bigB,
    const int* __restrict__ flags,
    u16* __restrict__ xb, u32* __restrict__ maskbits,
    const void* __restrict__ w0, const void* __restrict__ w1,
    const void* __restrict__ w2, const void* __restrict__ w3,
    u16* __restrict__ outQKV, u16* __restrict__ outO,
    const void* __restrict__ b0, const void* __restrict__ b1,
    const void* __restrict__ b2, const void* __restrict__ b3,
    float* __restrict__ biasf) {
  __shared__ float tile[32][33];
  const int bidg = blockIdx.x;
  const int t = threadIdx.x;
  const int amode = flags[1];

  if (bidg < 8192) {
    const void* x = flags[0] ? bigB : bigA;
    int i = (bidg * 256 + t) * 4;
    if (amode) {
      *(ushort4*)(xb + i) = *(const ushort4*)((const u16*)x + i);
    } else {
      float4 v = *(const float4*)((const float*)x + i);
      ushort4 o;
      o.x = f2b(v.x); o.y = f2b(v.y); o.z = f2b(v.z); o.w = f2b(v.w);
      *(ushort4*)(xb + i) = o;
    }
  } else if (bidg < 9216) {
    const void* mask = flags[0] ? bigA : bigB;
    const int mbyte = flags[2];
    const int lane = t & 63, wv = t >> 6;
    const u64 base0 = (u64)(bidg - 8192) * 8192;
#pragma unroll 4
    for (int k = 0; k < 32; k++) {
      u64 idx = base0 + k * 256 + t;
      int v;
      if (mbyte) v = ((const unsigned char*)mask)[idx] == 0;
      else       v = ((const u32*)mask)[idx] == 0;
      u64 b = __ballot(v);
      if (lane == 0) {
        u64 wbase = (base0 + k * 256 + wv * 64) >> 5;
        maskbits[wbase]     = (u32)b;
        maskbits[wbase + 1] = (u32)(b >> 32);
      }
    }
  } else if (bidg < 13312) {
    const int idx = bidg - 9216;
    const int z = idx >> 10;
    const int byi = (idx & 1023) >> 5;
    const int bxi = idx & 31;
    const void* in = (z == 0) ? w0 : (z == 1) ? w1 : (z == 2) ? w2 : w3;
    u16* out = (z < 3) ? (outQKV + (u64)z * EMB * EMB) : outO;
    const float scale = (z == 0) ? QSCALE : 1.0f;
    const int tx = t & 31;
    const int ty = t >> 5;
    const int bx = bxi * 32, by = byi * 32;
    if (amode) {
      const u16* inb = (const u16*)in;
#pragma unroll
      for (int r = ty; r < 32; r += 8)
        tile[r][tx] = b2f(inb[(u64)(by + r) * EMB + bx + tx]);
    } else {
      const float* inf = (const float*)in;
#pragma unroll
      for (int r = ty; r < 32; r += 8)
        tile[r][tx] = inf[(u64)(by + r) * EMB + bx + tx];
    }
    __syncthreads();
#pragma unroll
    for (int r = ty; r < 32; r += 8)
      out[(u64)(bx + r) * EMB + by + tx] = f2b(tile[tx][r] * scale);
  } else {
    const int widx = bidg - 13312;
    const void* ptrs[4] = {b0, b1, b2, b3};
    const void* p = ptrs[widx];
    const float scale = (widx == 0) ? QSCALE : 1.0f;
    for (int i = t; i < 1024; i += 256) {
      float v = amode ? b2f(((const u16*)p)[i]) : ((const float*)p)[i];
      biasf[widx * 1024 + i] = v * scale;
    }
  }
}

// ============================================================================
// GEMM v5: 128x128 tile, BK=64, 8 waves (4M x 2N, per-wave 32x64 =
// acc[2][4]), double-buffered LDS = 64 KB -> 2 BLOCKS/CU (was 96 KB /
// 1 block). Counted vmcnt(4) + raw s_barrier (T3-lite), setprio (T5),
// XOR-swizzled LDS via inverse-swizzled global_load_lds source (T2/m173).
// Rationale: at 1 block/CU the per-phase vmcnt wait (~200-550 cy load
// latency) is exposed; a second co-resident block covers it (m114
// mechanism; tile-space data: 128² @ 2-3 blk/CU = 912 TF > 256-class).
// Default blockIdx mapping (x-major round-robin L2-fits per XCD).
// Epilogues: Q/K LDS-staged contiguous stores; V -> Vt LDS transpose;
// fp32 linear for gemm_out.
// ============================================================================

// epilogue mode 0: QKV (Q/K head-scatter u16, V transposed [d][s]); 1: fp32
template <int OUTMODE>
__device__ __forceinline__ void gemm_core(
    const u16* __restrict__ X, const u16* __restrict__ Wt,
    const float* __restrict__ bias,
    u16* __restrict__ Qg, u16* __restrict__ Kg, u16* __restrict__ Vt,
    float* __restrict__ outf, int row0) {
  __shared__ __align__(16) u16 lds[2][(128 + 128) * 64];   // 64 KB
  const int t = threadIdx.x;
  const int lane = t & 63;
  const int w = t >> 6;                 // 0..7
  const int wr = w >> 1, wc = w & 1;    // wave tile: rows wr*32, cols wc*64
  const int l15 = lane & 15, l4 = lane >> 4;
  const int bM = blockIdx.x * 128, bN = blockIdx.y * 128;
  const int r7 = l15 & 7;
  const int cA = (l4 ^ r7) << 3;        // swizzled chunk for k-half 0
  const int cB = (l4 ^ r7 ^ 4) << 3;    // swizzled chunk for k-half 1

  floatx4 acc[2][4];
#pragma unroll
  for (int i = 0; i < 2; i++)
#pragma unroll
    for (int j = 0; j < 4; j++)
      acc[i][j] = (floatx4){0.f, 0.f, 0.f, 0.f};

  // staging: one glds16 covers 64 rows (8 rows/wave); chunk lane&7,
  // inverse-swizzled at the global source (LDS dst stays linear).
  const int srow = w * 8 + (lane >> 3);
  const int schk = ((lane & 7) ^ (lane >> 3)) << 3;
  const u16* Ap = X + (u64)(row0 + bM + srow) * EMB + schk;
  const u16* Bp = Wt + (u64)(bN + srow) * EMB + schk;
  u16* Ad0 = &lds[0][w * 512];
  u16* Bd0 = &lds[0][8192 + w * 512];
  u16* Ad1 = &lds[1][w * 512];
  u16* Bd1 = &lds[1][8192 + w * 512];

  auto stage = [&](u16* Ad, u16* Bd, int k0) {
    glds16(Ap + k0, Ad);
    glds16(Ap + k0 + 64 * EMB, Ad + 4096);
    glds16(Bp + k0, Bd);
    glds16(Bp + k0 + 64 * EMB, Bd + 4096);
  };

  auto compute = [&](const u16* __restrict__ Ab, const u16* __restrict__ Bb) {
    short8 bfr[4][2];
#pragma unroll
    for (int n = 0; n < 4; n++) {
      const int gr = (wc * 64 + n * 16 + l15) * 64;
      bfr[n][0] = *(const short8*)(&Bb[gr + cA]);
      bfr[n][1] = *(const short8*)(&Bb[gr + cB]);
    }
    short8 af2[2][2];
#pragma unroll
    for (int m = 0; m < 2; m++) {
      const int fr = (wr * 32 + m * 16 + l15) * 64;
      af2[m][0] = *(const short8*)(&Ab[fr + cA]);
      af2[m][1] = *(const short8*)(&Ab[fr + cB]);
    }
    __builtin_amdgcn_s_setprio(1);
#pragma unroll
    for (int m = 0; m < 2; m++)
#pragma unroll
      for (int n = 0; n < 4; n++) {
        acc[m][n] = __builtin_amdgcn_mfma_f32_16x16x32_bf16(
            af2[m][0], bfr[n][0], acc[m][n], 0, 0, 0);
        acc[m][n] = __builtin_amdgcn_mfma_f32_16x16x32_bf16(
            af2[m][1], bfr[n][1], acc[m][n], 0, 0, 0);
      }
    __builtin_amdgcn_s_setprio(0);
  };

  stage(Ad0, Bd0, 0);
  // 16 K-tiles, 2 per unrolled step; counted vmcnt(4) keeps next tile's
  // 4 loads in flight (T4); drains only at the tail.
  for (int k0 = 0; k0 < EMB; k0 += 128) {
    stage(Ad1, Bd1, k0 + 64);
    asm volatile("s_waitcnt vmcnt(4)" ::: "memory");
    asm volatile("s_barrier" ::: "memory");
    compute(&lds[0][0], &lds[0][8192]);
    asm volatile("s_barrier" ::: "memory");
    if (k0 + 128 < EMB) {
      stage(Ad0, Bd0, k0 + 128);
      asm volatile("s_waitcnt vmcnt(4)" ::: "memory");
    } else {
      asm volatile("s_waitcnt vmcnt(0)" ::: "memory");
    }
    asm volatile("s_barrier" ::: "memory");
    compute(&lds[1][0], &lds[1][8192]);
    asm volatile("s_barrier" ::: "memory");
  }

  if (OUTMODE == 0) {
    const int sec = bN >> 10;               // 0=Q,1=K,2=V (block-uniform)
    const int nb = bM >> 10;                // group-local batch
    if (sec < 2) {
      // Q/K: stage [s_local][d_local] in LDS ([128][136] u16, +8 pad),
      // then write each head's contiguous [s][d] region with 16B stores.
      u16* outp = (sec == 0) ? Qg : Kg;
      u16* ldt = &lds[0][0];                // 34.8 KB of the 64 KB block
#pragma unroll
      for (int n = 0; n < 4; n++) {
        const int cl = wc * 64 + n * 16 + l15;          // 0..127
        const float bv = bias[bN + cl];
#pragma unroll
        for (int m = 0; m < 2; m++) {
#pragma unroll
          for (int r = 0; r < 4; r++) {
            const int rl = wr * 32 + m * 16 + l4 * 4 + r;
            ldt[rl * 136 + cl] = f2b(acc[m][n][r] + bv);
          }
        }
      }
      __syncthreads();
      const int h0 = (bN & 1023) >> 6;
      const int s0 = bM & 1023;
#pragma unroll
      for (int hh = 0; hh < 2; hh++) {
        u16* basep = outp + ((u64)(nb * NH + h0 + hh) * SEQ + s0) * DKH;
#pragma unroll
        for (int kk = 0; kk < 2; kk++) {
          const int ci = t + 512 * kk;      // 0..1023 chunks of 8 elems
          const int s = ci >> 3, d0 = (ci & 7) * 8;
          *(uint4*)(basep + s * 64 + d0) =
              *(const uint4*)(&ldt[s * 136 + hh * 64 + d0]);
        }
      }
    } else {
      // V section: transpose through LDS ([128 d][128 s], XOR-swizzled),
      // write Vt[d][s] coalesced.
      u16* ldt = &lds[0][0];                // 32 KB of the 64 KB block
#pragma unroll
      for (int n = 0; n < 4; n++) {
        const int dl = wc * 64 + n * 16 + l15;          // 0..127
        const float bv = bias[bN + dl];
#pragma unroll
        for (int m = 0; m < 2; m++) {
          const int sb = wr * 32 + m * 16 + l4 * 4;     // mult of 4
          const int sp = sb ^ ((dl & 7) << 3);          // stays 4-aligned
          u32 w0 = (u32)f2b(acc[m][n][0] + bv) |
                   ((u32)f2b(acc[m][n][1] + bv) << 16);
          u32 w1 = (u32)f2b(acc[m][n][2] + bv) |
                   ((u32)f2b(acc[m][n][3] + bv) << 16);
          *(u32*)(&ldt[dl * 128 + sp])     = w0;
          *(u32*)(&ldt[dl * 128 + sp + 2]) = w1;
        }
      }
      __syncthreads();
      const int d  = t >> 2;          // 0..127
      const int sq = (t & 3) * 32;    // s quarter of 128
      const int s0 = bM & 1023;
      const int h = ((bN & 1023) >> 6) + (d >> 6);
      u16* vout = Vt + (u64)(nb * NH + h) * SEQ * DKH +
                  (u64)(d & 63) * SEQ + s0 + sq;
#pragma unroll
      for (int c = 0; c < 4; c++) {
        const int sc = sq + c * 8;
        const int scs = sc ^ ((d & 7) << 3);
        *(uint4*)(vout + c * 8) = *(const uint4*)(&ldt[d * 128 + scs]);
      }
    }
  } else {
#pragma unroll
    for (int n = 0; n < 4; n++) {
      int col = bN + wc * 64 + n * 16 + l15;
      float bv = bias[col];
#pragma unroll
      for (int m = 0; m < 2; m++) {
#pragma unroll
        for (int r = 0; r < 4; r++) {
          int row = bM + wr * 32 + m * 16 + l4 * 4 + r;
          outf[(u64)row * EMB + col] = acc[m][n][r] + bv;
        }
      }
    }
  }
}

__global__ __launch_bounds__(512, 4) void gemm_qkv(
    const u16* __restrict__ X, const u16* __restrict__ Wt,
    const float* __restrict__ bias,
    u16* __restrict__ Qg, u16* __restrict__ Kg, u16* __restrict__ Vt,
    int row0) {
  gemm_core<0>(X, Wt, bias, Qg, Kg, Vt, nullptr, row0);
}

__global__ __launch_bounds__(512, 4) void gemm_out(
    const u16* __restrict__ X, const u16* __restrict__ Wt,
    const float* __restrict__ bias, float* __restrict__ out) {
  gemm_core<1>(X, Wt, bias, nullptr, nullptr, nullptr, out, 0);
}

// ---------- MFMA flash attention (unchanged from round 6) ----------
__global__ __launch_bounds__(512, 4) void attn_mfma(
    const u16* __restrict__ Q, const u16* __restrict__ K,
    const u16* __restrict__ Vt, const u32* __restrict__ maskbits,
    int b0, u16* __restrict__ ctx) {
  __shared__ __align__(16) u16 Ks[2][64 * 64];
  __shared__ __align__(16) u16 Vs[64 * 64];
  __shared__ __align__(16) u16 Ps[256 * 64];

  const int t = threadIdx.x;
  const int lane = t & 63, w = t >> 6;
  const int l15 = lane & 15, l4 = lane >> 4;
  const int bid = blockIdx.x;
  const int h = bid & 15;
  const int qt = (bid >> 4) & 3;
  const int n = bid >> 6;
  const int nh = n * NH + h;
  const int q0 = qt * 256;
  const u64 hoff = (u64)nh * SEQ * DKH;

  const int r7 = l15 & 7;
  const int cA = (l4 ^ r7) << 3;
  const int cB = (l4 ^ r7 ^ 4) << 3;

  const int rt = w * 8 + (lane >> 3);
  const int chk = ((lane & 7) ^ (lane >> 3)) << 3;
  const u16* Kp = K + hoff + (u64)rt * DKH + chk;
  const u16* Vp = Vt + hoff + (u64)rt * SEQ + chk;
  const int ldsO = w * 512;

  short8 qf[2][2];
  {
    const u16* qpA = Q + hoff + (u64)(q0 + w * 32 + l15) * DKH + l4 * 8;
    qf[0][0] = *(const short8*)(qpA);
    qf[0][1] = *(const short8*)(qpA + 32);
    const u16* qpB = qpA + 16 * DKH;
    qf[1][0] = *(const short8*)(qpB);
    qf[1][1] = *(const short8*)(qpB + 32);
  }

  short8 ones;
#pragma unroll
  for (int e = 0; e < 8; e++) ones[e] = (short)0x3F80;

  floatx4 o[2][4];
#pragma unroll
  for (int s = 0; s < 2; s++)
#pragma unroll
    for (int j = 0; j < 4; j++) o[s][j] = (floatx4){0.f, 0.f, 0.f, 0.f};
  floatx4 osum[2];
  osum[0] = (floatx4){0.f, 0.f, 0.f, 0.f};
  osum[1] = (floatx4){0.f, 0.f, 0.f, 0.f};

  const u64 mrow0 = ((u64)((b0 + n) * SEQ + q0 + w * 32 + l15)) * 32;
  const u64 mrow1 = mrow0 + 16 * 32;
  const int pq0 = w * 32 + l15;
  const int pq1 = pq0 + 16;
  const int pc0 = (l4 * 4) ^ (r7 << 3);

  glds16(Kp, &Ks[0][ldsO]);
  glds16(Vp, &Vs[ldsO]);
  __syncthreads();

  int cur = 0;
  for (int kc = 0; kc < SEQ; kc += 64) {
    if (kc > 0) glds16(Vp + kc, &Vs[ldsO]);
    const int havek = (kc + 64 < SEQ);
    if (havek) glds16(Kp + (kc + 64) * DKH, &Ks[cur ^ 1][ldsO]);

    const u64 mb0 = *(const u64*)(maskbits + mrow0 + (kc >> 5));
    const u64 mb1 = *(const u64*)(maskbits + mrow1 + (kc >> 5));
    const u16* Kc = &Ks[cur][0];

    __builtin_amdgcn_s_setprio(1);
#pragma unroll
    for (int j = 0; j < 4; j++) {
      const int rb = (j * 16 + l15) * 64;
      short8 kb0 = *(const short8*)(&Kc[rb + cA]);
      short8 kb1 = *(const short8*)(&Kc[rb + cB]);
      floatx4 s0 = (floatx4){0.f, 0.f, 0.f, 0.f};
      floatx4 s1 = (floatx4){0.f, 0.f, 0.f, 0.f};
      s0 = __builtin_amdgcn_mfma_f32_16x16x32_bf16(kb0, qf[0][0], s0, 0, 0, 0);
      s0 = __builtin_amdgcn_mfma_f32_16x16x32_bf16(kb1, qf[0][1], s0, 0, 0, 0);
      s1 = __builtin_amdgcn_mfma_f32_16x16x32_bf16(kb0, qf[1][0], s1, 0, 0, 0);
      s1 = __builtin_amdgcn_mfma_f32_16x16x32_bf16(kb1, qf[1][1], s1, 0, 0, 0);

      const u32 mj0 = (u32)(mb0 >> (j * 16 + l4 * 4));
      const u32 mj1 = (u32)(mb1 >> (j * 16 + l4 * 4));
      float p00 = __uint_as_float(
          __float_as_uint(__builtin_amdgcn_exp2f(s0[0])) &
          (u32)__builtin_amdgcn_sbfe(mj0, 0, 1));
      float p01 = __uint_as_float(
          __float_as_uint(__builtin_amdgcn_exp2f(s0[1])) &
          (u32)__builtin_amdgcn_sbfe(mj0, 1, 1));
      float p02 = __uint_as_float(
          __float_as_uint(__builtin_amdgcn_exp2f(s0[2])) &
          (u32)__builtin_amdgcn_sbfe(mj0, 2, 1));
      float p03 = __uint_as_float(
          __float_as_uint(__builtin_amdgcn_exp2f(s0[3])) &
          (u32)__builtin_amdgcn_sbfe(mj0, 3, 1));
      float p10 = __uint_as_float(
          __float_as_uint(__builtin_amdgcn_exp2f(s1[0])) &
          (u32)__builtin_amdgcn_sbfe(mj1, 0, 1));
      float p11 = __uint_as_float(
          __float_as_uint(__builtin_amdgcn_exp2f(s1[1])) &
          (u32)__builtin_amdgcn_sbfe(mj1, 1, 1));
      float p12 = __uint_as_float(
          __float_as_uint(__builtin_amdgcn_exp2f(s1[2])) &
          (u32)__builtin_amdgcn_sbfe(mj1, 2, 1));
      float p13 = __uint_as_float(
          __float_as_uint(__builtin_amdgcn_exp2f(s1[3])) &
          (u32)__builtin_amdgcn_sbfe(mj1, 3, 1));

      uint2 pk0, pk1;
      asm("v_cvt_pk_bf16_f32 %0, %1, %2" : "=v"(pk0.x) : "v"(p00), "v"(p01));
      asm("v_cvt_pk_bf16_f32 %0, %1, %2" : "=v"(pk0.y) : "v"(p02), "v"(p03));
      asm("v_cvt_pk_bf16_f32 %0, %1, %2" : "=v"(pk1.x) : "v"(p10), "v"(p11));
      asm("v_cvt_pk_bf16_f32 %0, %1, %2" : "=v"(pk1.y) : "v"(p12), "v"(p13));
      const int pcol = (j * 16) ^ pc0;
      *(uint2*)(&Ps[pq0 * 64 + pcol]) = pk0;
      *(uint2*)(&Ps[pq1 * 64 + pcol]) = pk1;
    }

    if (havek) asm volatile("s_waitcnt vmcnt(1)" ::: "memory");
    else       asm volatile("s_waitcnt vmcnt(0)" ::: "memory");
    __builtin_amdgcn_s_barrier();

    short8 pa[2][2];
    pa[0][0] = *(const short8*)(&Ps[pq0 * 64 + cA]);
    pa[0][1] = *(const short8*)(&Ps[pq0 * 64 + cB]);
    pa[1][0] = *(const short8*)(&Ps[pq1 * 64 + cA]);
    pa[1][1] = *(const short8*)(&Ps[pq1 * 64 + cB]);
#pragma unroll
    for (int j = 0; j < 4; j++) {
      const int rb = (j * 16 + l15) * 64;
      short8 vb0 = *(const short8*)(&Vs[rb + cA]);
      short8 vb1 = *(const short8*)(&Vs[rb + cB]);
      o[0][j] = __builtin_amdgcn_mfma_f32_16x16x32_bf16(pa[0][0], vb0, o[0][j], 0, 0, 0);
      o[0][j] = __builtin_amdgcn_mfma_f32_16x16x32_bf16(pa[0][1], vb1, o[0][j], 0, 0, 0);
      o[1][j] = __builtin_amdgcn_mfma_f32_16x16x32_bf16(pa[1][0], vb0, o[1][j], 0, 0, 0);
      o[1][j] = __builtin_amdgcn_mfma_f32_16x16x32_bf16(pa[1][1], vb1, o[1][j], 0, 0, 0);
    }
    osum[0] = __builtin_amdgcn_mfma_f32_16x16x32_bf16(pa[0][0], ones, osum[0], 0, 0, 0);
    osum[0] = __builtin_amdgcn_mfma_f32_16x16x32_bf16(pa[0][1], ones, osum[0], 0, 0, 0);
    osum[1] = __builtin_amdgcn_mfma_f32_16x16x32_bf16(pa[1][0], ones, osum[1], 0, 0, 0);
    osum[1] = __builtin_amdgcn_mfma_f32_16x16x32_bf16(pa[1][1], ones, osum[1], 0, 0, 0);
    __builtin_amdgcn_s_setprio(0);

    __syncthreads();
    cur ^= 1;
  }

#pragma unroll
  for (int s = 0; s < 2; s++) {
#pragma unroll
    for (int r = 0; r < 4; r++) {
      float invr = 1.0f / fmaxf(osum[s][r], 1e-30f);
      int q = q0 + w * 32 + s * 16 + l4 * 4 + r;
      u64 base = ((u64)(n * SEQ + q)) * EMB + h * DKH + l15;
#pragma unroll
      for (int j = 0; j < 4; j++)
        ctx[base + j * 16] = f2b(o[s][j][r] * invr);
    }
  }
}

extern "C" void kernel_launch(void* const* d_in, const int* in_sizes, int n_in,
                              void* d_out, int out_size, void* d_ws, size_t ws_size,
                              hipStream_t stream) {
  int bigI[2] = {0, 1}, wI[4] = {2, 4, 6, 8}, bI[4] = {3, 5, 7, 9};
  int nb = 0, nw = 0, nbi = 0;
  for (int i = 0; i < n_in; i++) {
    if (in_sizes[i] == 8388608) { if (nb < 2) bigI[nb++] = i; }
    else if (in_sizes[i] == 1048576) { if (nw < 4) wI[nw++] = i; }
    else if (in_sizes[i] == 1024) { if (nbi < 4) bI[nbi++] = i; }
  }
  int oq = 0, ok = 1, ov = 2, oo = 3;
  if (nb == 2 && bigI[0] == 4 && bigI[1] == 9) { oq = 2; ok = 0; ov = 3; oo = 1; }

  const void* bigA = d_in[bigI[0]];
  const void* bigB = d_in[bigI[1]];
  const void* Wq = d_in[wI[oq]];
  const void* Wk = d_in[wI[ok]];
  const void* Wv = d_in[wI[ov]];
  const void* Wo = d_in[wI[oo]];
  const void* bq = d_in[bI[oq]];
  const void* bk = d_in[bI[ok]];
  const void* bv = d_in[bI[ov]];
  const void* bo = d_in[bI[oo]];

  char* ws = (char*)d_ws;
  u16* WtQKV = (u16*)ws;
  u16* WtO   = (u16*)(ws + (6ull << 20));
  float* biasf = (float*)(ws + (8ull << 20));
  int* flags = (int*)(ws + (8ull << 20) + 16384);
  u32* maskbits = (u32*)(ws + (8ull << 20) + 65536);
  u16* xb = (u16*)(ws + (10ull << 20));
  char* grp = ws + (26ull << 20);

  int G = 1;
  for (int g = 8; g >= 1; g >>= 1) {
    if (ws_size >= (26ull << 20) + (u64)g * (8ull << 20)) { G = g; break; }
  }
  const u64 gsz = (u64)G * (2ull << 20);
  u16* Qg = (u16*)grp;
  u16* Kg = (u16*)(grp + gsz);
  u16* ctx = (u16*)(grp + 2 * gsz);
  u16* Vt = (u16*)(grp + 3 * gsz);

  dim3 tb(256);

  probe_inputs<<<dim3(1), tb, 0, stream>>>((const u32*)bigA, (const u32*)bigB, flags);

  // fused preprocessing: 8192 convert_x + 1024 maskbits + 4096 w4 + 4 biases
  preprocess<<<dim3(13316), tb, 0, stream>>>(
      bigA, bigB, flags, xb, maskbits,
      Wq, Wk, Wv, Wo, WtQKV, WtO,
      bq, bk, bv, bo, biasf);

  for (int b0 = 0; b0 < 8; b0 += G) {
    int row0 = b0 * 1024;
    gemm_qkv<<<dim3(8 * G, 24), dim3(512), 0, stream>>>(xb, WtQKV, biasf, Qg, Kg, Vt, row0);

    attn_mfma<<<dim3(G * 16 * 4), dim3(512), 0, stream>>>(Qg, Kg, Vt, maskbits, b0, ctx);

    gemm_out<<<dim3(8 * G, 8), dim3(512), 0, stream>>>(ctx, WtO, biasf + 3072,
                                                       (float*)d_out + (u64)row0 * EMB);
  }
}